// Round 1
// baseline (475.290 us; speedup 1.0000x reference)
//
#include <hip/hip_runtime.h>

#define PLANE (384 * 384)
#define TH 16
#define TW 64
#define TROW 68                  // tile row padded to multiple of 4 floats (16B align)
#define TROWS 18                 // TH + 2 halo rows
#define CPLANE (TROWS * TROW)    // 1224 floats per channel plane in LDS

// ---------------- Pass 1: abs-max of x (and of weight, in block 0) ----------
__global__ __launch_bounds__(256) void amax_kernel(
    const float* __restrict__ x, const float* __restrict__ w,
    unsigned int* __restrict__ ws)
{
    const long n4 = 9437184;  // 32*8*384*384 / 4
    long tid = (long)blockIdx.x * blockDim.x + threadIdx.x;
    long stride = (long)gridDim.x * blockDim.x;
    const float4* x4 = (const float4*)x;

    float m = 0.f;
    for (long i = tid; i < n4; i += stride) {
        float4 v = x4[i];
        m = fmaxf(m, fmaxf(fmaxf(fabsf(v.x), fabsf(v.y)),
                           fmaxf(fabsf(v.z), fabsf(v.w))));
    }
    // wave-64 reduction
    #pragma unroll
    for (int off = 32; off > 0; off >>= 1)
        m = fmaxf(m, __shfl_down(m, off, 64));
    if ((threadIdx.x & 63) == 0)
        atomicMax(&ws[0], __float_as_uint(m));  // floats >= 0: uint-monotone

    if (blockIdx.x == 0) {
        float mw = 0.f;
        for (int j = threadIdx.x; j < 576; j += 256)
            mw = fmaxf(mw, fabsf(w[j]));
        #pragma unroll
        for (int off = 32; off > 0; off >>= 1)
            mw = fmaxf(mw, __shfl_down(mw, off, 64));
        if ((threadIdx.x & 63) == 0)
            atomicMax(&ws[1], __float_as_uint(mw));
    }
}

// ---------------- Pass 2: quantize + 3x3 conv + dequant + bias --------------
// Block: 256 threads; computes a TH x TW output tile for one image n, all 8
// output channels. Each thread: one 4-pixel row strip x 8 channels = 32 acc.
__global__ __launch_bounds__(256) void conv_kernel(
    const float* __restrict__ x, const float* __restrict__ w,
    const float* __restrict__ bias, const unsigned int* __restrict__ ws,
    float* __restrict__ out)
{
    __shared__ __align__(16) float sIn[8 * CPLANE];  // 39168 B
    __shared__ __align__(16) float sW[576];          // [c][r][s][k]
    __shared__ float sB[8];

    const float amax_x = __uint_as_float(ws[0]);
    const float amax_w = __uint_as_float(ws[1]);
    const float s_x = 127.0f / amax_x;
    const float s_w = 127.0f / amax_w;
    const float inv = 1.0f / (s_x * s_w);

    const int bid = blockIdx.x;
    const int bx = bid % 6;             // 384/TW
    const int by = (bid / 6) % 24;      // 384/TH
    const int n  = bid / (6 * 24);
    const int h0 = by * TH;
    const int w0 = bx * TW;
    const int tid = threadIdx.x;

    // quantize + repack weights: w[k][c][r][s] -> sW[(c*9 + r*3 + s)*8 + k]
    for (int i = tid; i < 576; i += 256) {
        int k = i / 72;
        int rem = i - k * 72;           // c*9 + r*3 + s
        float qv = fminf(fmaxf(rintf(w[i] * s_w), -127.f), 127.f);
        sW[rem * 8 + k] = qv;
    }
    if (tid < 8) sB[tid] = bias[tid];

    // load + quantize input tile: 8 ch x 18 rows x 66 cols (halo, zero-pad)
    const float* xn = x + (long)n * 8 * PLANE;
    for (int i = tid; i < 8 * TROWS * 66; i += 256) {
        int c = i / (TROWS * 66);
        int rem = i - c * (TROWS * 66);
        int yy = rem / 66;
        int xx = rem - yy * 66;
        int gy = h0 - 1 + yy;
        int gx = w0 - 1 + xx;
        float v = 0.f;
        if ((unsigned)gy < 384u && (unsigned)gx < 384u)
            v = xn[c * PLANE + gy * 384 + gx];
        sIn[c * CPLANE + yy * TROW + xx] =
            fminf(fmaxf(rintf(v * s_x), -127.f), 127.f);
    }
    __syncthreads();

    const int sy  = tid >> 4;           // 0..15
    const int sxi = (tid & 15) << 2;    // 0,4,...,60 (16B-aligned col)

    float acc[8][4];
    #pragma unroll
    for (int k = 0; k < 8; ++k)
        #pragma unroll
        for (int j = 0; j < 4; ++j) acc[k][j] = 0.f;

    #pragma unroll 1
    for (int c = 0; c < 8; ++c) {
        #pragma unroll
        for (int r = 0; r < 3; ++r) {
            const float* rowp = &sIn[c * CPLANE + (sy + r) * TROW + sxi];
            float4 a4 = *(const float4*)rowp;        // ds_read_b128
            float2 b2 = *(const float2*)(rowp + 4);  // ds_read_b64
            float v[6] = {a4.x, a4.y, a4.z, a4.w, b2.x, b2.y};
            const float* wp = &sW[(c * 3 + r) * 24];
            #pragma unroll
            for (int s = 0; s < 3; ++s) {
                float4 w0v = *(const float4*)(wp + s * 8);      // broadcast
                float4 w1v = *(const float4*)(wp + s * 8 + 4);
                float wk[8] = {w0v.x, w0v.y, w0v.z, w0v.w,
                               w1v.x, w1v.y, w1v.z, w1v.w};
                #pragma unroll
                for (int k = 0; k < 8; ++k)
                    #pragma unroll
                    for (int j = 0; j < 4; ++j)
                        acc[k][j] = fmaf(v[j + s], wk[k], acc[k][j]);
            }
        }
    }

    float* on = out + (long)n * 8 * PLANE + (long)(h0 + sy) * 384 + (w0 + sxi);
    #pragma unroll
    for (int k = 0; k < 8; ++k) {
        float4 o;
        o.x = fmaf(acc[k][0], inv, sB[k]);
        o.y = fmaf(acc[k][1], inv, sB[k]);
        o.z = fmaf(acc[k][2], inv, sB[k]);
        o.w = fmaf(acc[k][3], inv, sB[k]);
        *(float4*)(on + (long)k * PLANE) = o;
    }
}

extern "C" void kernel_launch(void* const* d_in, const int* in_sizes, int n_in,
                              void* d_out, int out_size, void* d_ws, size_t ws_size,
                              hipStream_t stream) {
    const float* x   = (const float*)d_in[0];
    const float* w   = (const float*)d_in[1];
    const float* b   = (const float*)d_in[2];
    float* out       = (float*)d_out;
    unsigned int* ws = (unsigned int*)d_ws;

    // d_ws is poisoned 0xAA (huge as uint) -> zero the two amax slots first.
    hipMemsetAsync(ws, 0, 2 * sizeof(unsigned int), stream);
    amax_kernel<<<2048, 256, 0, stream>>>(x, w, ws);
    conv_kernel<<<32 * 24 * 6, 256, 0, stream>>>(x, w, b, ws, out);
}

// Round 2
// 323.713 us; speedup vs baseline: 1.4682x; 1.4682x over previous
//
#include <hip/hip_runtime.h>

#define PLANE (384 * 384)
#define TH 16
#define TW 64
#define TROWS 18     // TH + 2 halo rows
#define TCOLS 66     // TW + 2 halo cols; row = 132 dwords, 132 % 32 = 4 (bank rotate)

#if __has_builtin(__builtin_amdgcn_sdot4)
__device__ __forceinline__ int sdot4(int a, int b, int c) {
    return __builtin_amdgcn_sdot4(a, b, c, false);
}
#else
__device__ __forceinline__ int sdot4(int a, int b, int c) {
    #pragma unroll
    for (int i = 0; i < 4; ++i)
        c += ((a << (24 - 8 * i)) >> 24) * ((b << (24 - 8 * i)) >> 24);
    return c;
}
#endif

// ---------------- Pass 1: abs-max of x (and of weight, in block 0) ----------
__global__ __launch_bounds__(256) void amax_kernel(
    const float* __restrict__ x, const float* __restrict__ w,
    unsigned int* __restrict__ ws)
{
    __shared__ float red[4];
    const long n4 = 9437184;  // 32*8*384*384 / 4
    long tid = (long)blockIdx.x * blockDim.x + threadIdx.x;
    long stride = (long)gridDim.x * blockDim.x;
    const float4* x4 = (const float4*)x;

    float m = 0.f;
    for (long i = tid; i < n4; i += stride) {
        float4 v = x4[i];
        m = fmaxf(m, fmaxf(fmaxf(fabsf(v.x), fabsf(v.y)),
                           fmaxf(fabsf(v.z), fabsf(v.w))));
    }
    #pragma unroll
    for (int off = 32; off > 0; off >>= 1)
        m = fmaxf(m, __shfl_down(m, off, 64));
    if ((threadIdx.x & 63) == 0) red[threadIdx.x >> 6] = m;
    __syncthreads();
    if (threadIdx.x == 0) {
        float bm = fmaxf(fmaxf(red[0], red[1]), fmaxf(red[2], red[3]));
        atomicMax(&ws[0], __float_as_uint(bm));  // floats >= 0: uint-monotone
    }

    if (blockIdx.x == 0) {
        float mw = 0.f;
        for (int j = threadIdx.x; j < 576; j += 256)
            mw = fmaxf(mw, fabsf(w[j]));
        #pragma unroll
        for (int off = 32; off > 0; off >>= 1)
            mw = fmaxf(mw, __shfl_down(mw, off, 64));
        if ((threadIdx.x & 63) == 0)
            atomicMax(&ws[1], __float_as_uint(mw));
    }
}

// ------- Pass 2: quantize -> packed int8 -> sdot4 conv -> dequant + bias ----
// Block: 256 threads, one 16x64 output tile, all 8 output channels.
// LDS input tile: 18 x 66 px, each px = 8 channels packed as 2 dwords (int8x4).
// Thread (ty,tx): 4-px strip x 8 k; inner dot over channels via v_dot4_i32_i8.
__global__ __launch_bounds__(256) void conv_kernel(
    const float* __restrict__ x, const float* __restrict__ w,
    const float* __restrict__ bias, const unsigned int* __restrict__ ws,
    float* __restrict__ out)
{
    __shared__ __align__(16) unsigned sIn[TROWS * TCOLS * 2];  // 9504 B
    __shared__ __align__(16) unsigned sWq[9 * 8 * 2];          // [p][k][half], 576 B
    __shared__ float sB[8];

    const float amax_x = __uint_as_float(ws[0]);
    const float amax_w = __uint_as_float(ws[1]);
    const float s_x = 127.0f / amax_x;
    const float s_w = 127.0f / amax_w;
    const float inv = 1.0f / (s_x * s_w);

    const int bid = blockIdx.x;
    const int bx = bid % 6;             // 384/TW
    const int by = (bid / 6) % 24;      // 384/TH
    const int n  = bid / (6 * 24);
    const int h0 = by * TH;
    const int w0 = bx * TW;
    const int tid = threadIdx.x;

    // quantize + pack weights: w[k][c][p] -> sWq[p*16 + k*2 + h], bytes c=4h..4h+3
    if (tid < 144) {
        int h = tid & 1, k = (tid >> 1) & 7, p = tid >> 4;
        unsigned pk = 0;
        #pragma unroll
        for (int j = 0; j < 4; ++j) {
            int c = 4 * h + j;
            float qv = fminf(fmaxf(rintf(w[k * 72 + c * 9 + p] * s_w), -127.f), 127.f);
            int qi = (int)qv;
            pk |= ((unsigned)(qi & 0xff)) << (8 * j);
        }
        sWq[p * 16 + k * 2 + h] = pk;
    }
    if (tid < 8) sB[tid] = bias[tid];

    // stage input tile: per-pixel, 8 strided b32 loads, quantize, pack, b64 write
    const float* xn = x + (long)n * 8 * PLANE;
    for (int q = tid; q < TROWS * TCOLS; q += 256) {
        int yy = q / TCOLS;
        int xx = q - yy * TCOLS;
        int gy = h0 - 1 + yy;
        int gx = w0 - 1 + xx;
        bool ok = ((unsigned)gy < 384u) && ((unsigned)gx < 384u);
        long base = (long)gy * 384 + gx;
        unsigned lo = 0, hi = 0;
        #pragma unroll
        for (int c = 0; c < 8; ++c) {
            float v = 0.f;
            if (ok) v = xn[(long)c * PLANE + base];
            float qv = fminf(fmaxf(rintf(v * s_x), -127.f), 127.f);
            int qi = (int)qv;
            if (c < 4) lo |= ((unsigned)(qi & 0xff)) << (8 * c);
            else       hi |= ((unsigned)(qi & 0xff)) << (8 * (c - 4));
        }
        *(uint2*)&sIn[2 * q] = make_uint2(lo, hi);  // ds_write_b64, 2-bank stride: free
    }
    __syncthreads();

    const int ty = tid >> 4;   // 0..15 output row
    const int tx = tid & 15;   // output cols 4*tx .. 4*tx+3

    int acc[4][8];
    #pragma unroll
    for (int i = 0; i < 4; ++i)
        #pragma unroll
        for (int k = 0; k < 8; ++k) acc[i][k] = 0;

    #pragma unroll
    for (int r = 0; r < 3; ++r) {
        // 6 input px (12 dwords) via 3 x ds_read_b128; xx = 4*tx .. 4*tx+5
        const uint4* ip = (const uint4*)&sIn[((ty + r) * TCOLS + 4 * tx) * 2];
        uint4 i0 = ip[0], i1 = ip[1], i2 = ip[2];
        unsigned d[12] = {i0.x, i0.y, i0.z, i0.w,
                          i1.x, i1.y, i1.z, i1.w,
                          i2.x, i2.y, i2.z, i2.w};
        #pragma unroll
        for (int s = 0; s < 3; ++s) {
            const uint4* wp = (const uint4*)&sWq[(r * 3 + s) * 16];  // broadcast
            uint4 wa = wp[0], wb = wp[1], wc = wp[2], wd = wp[3];
            unsigned wk[16] = {wa.x, wa.y, wa.z, wa.w, wb.x, wb.y, wb.z, wb.w,
                               wc.x, wc.y, wc.z, wc.w, wd.x, wd.y, wd.z, wd.w};
            #pragma unroll
            for (int k = 0; k < 8; ++k)
                #pragma unroll
                for (int i = 0; i < 4; ++i)
                    acc[i][k] = sdot4((int)d[2 * (i + s) + 1], (int)wk[2 * k + 1],
                                sdot4((int)d[2 * (i + s)],     (int)wk[2 * k],
                                      acc[i][k]));
        }
    }

    float* on = out + (long)n * 8 * PLANE + (long)(h0 + ty) * 384 + (w0 + 4 * tx);
    #pragma unroll
    for (int k = 0; k < 8; ++k) {
        float4 o;
        o.x = fmaf((float)acc[0][k], inv, sB[k]);
        o.y = fmaf((float)acc[1][k], inv, sB[k]);
        o.z = fmaf((float)acc[2][k], inv, sB[k]);
        o.w = fmaf((float)acc[3][k], inv, sB[k]);
        *(float4*)(on + (long)k * PLANE) = o;
    }
}

extern "C" void kernel_launch(void* const* d_in, const int* in_sizes, int n_in,
                              void* d_out, int out_size, void* d_ws, size_t ws_size,
                              hipStream_t stream) {
    const float* x   = (const float*)d_in[0];
    const float* w   = (const float*)d_in[1];
    const float* b   = (const float*)d_in[2];
    float* out       = (float*)d_out;
    unsigned int* ws = (unsigned int*)d_ws;

    // d_ws is poisoned 0xAA (huge as uint) -> zero the two amax slots first.
    hipMemsetAsync(ws, 0, 2 * sizeof(unsigned int), stream);
    amax_kernel<<<2048, 256, 0, stream>>>(x, w, ws);
    conv_kernel<<<32 * 24 * 6, 256, 0, stream>>>(x, w, b, ws, out);
}